// Round 3
// baseline (1260.834 us; speedup 1.0000x reference)
//
#include <hip/hip_runtime.h>

#define LNUM 4
#define DIM 1024
#define NH 16
#define VOCAB 32000
#define SEQ 2048
#define HIDD 2816

typedef _Float16 f16;
typedef _Float16 h8_t __attribute__((ext_vector_type(8)));
typedef _Float16 h4_t __attribute__((ext_vector_type(4)));
typedef float f4_t __attribute__((ext_vector_type(4)));

#define MFMA(a, b, c) __builtin_amdgcn_mfma_f32_16x16x32_f16(a, b, c, 0, 0, 0)

__device__ __forceinline__ void async16(void* lds, const void* g) {
  __builtin_amdgcn_global_load_lds(
      (const __attribute__((address_space(1))) void*)g,
      (__attribute__((address_space(3))) void*)lds, 16, 0, 0);
}

// ---------------- fused per-layer fp32 -> fp16 weight cast ----------------
__global__ __launch_bounds__(256) void cast_layer_k(
    const float* __restrict__ wq, const float* __restrict__ wk,
    const float* __restrict__ wv, const float* __restrict__ wo,
    const float* __restrict__ w1, const float* __restrict__ w3,
    const float* __restrict__ w2, f16* __restrict__ wqkv,
    f16* __restrict__ wod, f16* __restrict__ w13, f16* __restrict__ w2d) {
  const int DD4c = DIM * DIM / 4, HD4c = HIDD * DIM / 4;
  int i = blockIdx.x * 256 + threadIdx.x;  // total 4*DD4c + 3*HD4c = 3211264
  const float* s;
  f16* d;
  int si, di;
  if (i < 3 * DD4c) {
    d = wqkv;
    di = i;
    if (i < DD4c) {
      s = wq; si = i;
    } else if (i < 2 * DD4c) {
      s = wk; si = i - DD4c;
    } else {
      s = wv; si = i - 2 * DD4c;
    }
  } else if (i < 4 * DD4c) {
    s = wo; si = i - 3 * DD4c; d = wod; di = si;
  } else if (i < 4 * DD4c + HD4c) {
    s = w1; si = i - 4 * DD4c; d = w13; di = si;
  } else if (i < 4 * DD4c + 2 * HD4c) {
    s = w3; si = i - 4 * DD4c - HD4c; d = w13; di = si + HD4c;
  } else {
    s = w2; si = i - 4 * DD4c - 2 * HD4c; d = w2d; di = si;
  }
  float4 v = ((const float4*)s)[si];
  ((h4_t*)d)[di] = (h4_t){(f16)v.x, (f16)v.y, (f16)v.z, (f16)v.w};
}

// ---------------- embedding gather ----------------
__global__ __launch_bounds__(256) void embed_k(const int* __restrict__ tok,
                                               const float* __restrict__ emb,
                                               float* __restrict__ h) {
  const int s = blockIdx.x, t = threadIdx.x;
  ((float4*)(h + (size_t)s * DIM))[t] =
      ((const float4*)(emb + (size_t)tok[s] * DIM))[t];
}

// ---------------- rope table (cos,sin per (s,f)) ----------------
__global__ void rope_tab_k(float* __restrict__ tab) {
  int i = blockIdx.x * 256 + threadIdx.x;
  if (i >= SEQ * 32) return;
  int s = i >> 5, f = i & 31;
  float inv = powf(10000.f, -(float)f * (1.f / 32.f));
  float a = (float)s * inv;
  float sn, c;
  sincosf(a, &sn, &c);
  tab[i * 2] = c;
  tab[i * 2 + 1] = sn;
}

// ---------------- rope apply in-place on q,k parts of qkv ----------------
__global__ __launch_bounds__(256) void rope_k(f16* __restrict__ qkv,
                                              const float* __restrict__ tab) {
  int i = blockIdx.x * 256 + threadIdx.x;  // SEQ*2*NH*32 = 2M
  int f = i & 31, hh = (i >> 5) & 15, part = (i >> 9) & 1, s = i >> 10;
  size_t base = (size_t)s * 3072 + part * 1024 + hh * 64 + f * 2;
  float xr = (float)qkv[base], xi = (float)qkv[base + 1];
  float c = tab[(s * 32 + f) * 2], sn = tab[(s * 32 + f) * 2 + 1];
  qkv[base] = (f16)(xr * c - xi * sn);
  qkv[base + 1] = (f16)(xr * sn + xi * c);
}

// ---------------- rmsnorm: fp32 h row -> fp16 out ----------------
__global__ __launch_bounds__(256) void rmsnorm_k(const float* __restrict__ h,
                                                 const float* __restrict__ w,
                                                 f16* __restrict__ out) {
  const int s = blockIdx.x, t = threadIdx.x;
  float4 v = ((const float4*)(h + (size_t)s * DIM))[t];
  float ss = v.x * v.x + v.y * v.y + v.z * v.z + v.w * v.w;
#pragma unroll
  for (int d = 1; d < 64; d <<= 1) ss += __shfl_xor(ss, d);
  __shared__ float red[4];
  if ((t & 63) == 0) red[t >> 6] = ss;
  __syncthreads();
  float tot = red[0] + red[1] + red[2] + red[3];
  float sc = rsqrtf(tot * (1.f / (float)DIM) + 1e-5f);
  float4 wv = ((const float4*)w)[t];
  ((h4_t*)(out + (size_t)s * DIM))[t] =
      (h4_t){(f16)(v.x * sc * wv.x), (f16)(v.y * sc * wv.y),
             (f16)(v.z * sc * wv.z), (f16)(v.w * sc * wv.w)};
}

// ---------------- final rmsnorm (row SEQ-1) -> fp32 ----------------
__global__ __launch_bounds__(256) void final_norm_k(const float* __restrict__ h,
                                                    const float* __restrict__ w,
                                                    float* __restrict__ hn) {
  const int t = threadIdx.x;
  float4 v = ((const float4*)(h + (size_t)(SEQ - 1) * DIM))[t];
  float ss = v.x * v.x + v.y * v.y + v.z * v.z + v.w * v.w;
#pragma unroll
  for (int d = 1; d < 64; d <<= 1) ss += __shfl_xor(ss, d);
  __shared__ float red[4];
  if ((t & 63) == 0) red[t >> 6] = ss;
  __syncthreads();
  float tot = red[0] + red[1] + red[2] + red[3];
  float sc = rsqrtf(tot * (1.f / (float)DIM) + 1e-5f);
  float4 wv = ((const float4*)w)[t];
  ((float4*)hn)[t] = make_float4(v.x * sc * wv.x, v.y * sc * wv.y,
                                 v.z * sc * wv.z, v.w * sc * wv.w);
}

// ---------------- logits: out[v] = hn . emb[v] (fp32) ----------------
__global__ __launch_bounds__(256) void logits_k(const float* __restrict__ hn,
                                                const float* __restrict__ emb,
                                                float* __restrict__ out) {
  const int v = blockIdx.x * 4 + (threadIdx.x >> 6);
  const int lane = threadIdx.x & 63;
  const float4* er = (const float4*)(emb + (size_t)v * DIM);
  const float4* hr = (const float4*)hn;
  float s = 0.f;
#pragma unroll
  for (int i = 0; i < 4; i++) {
    float4 a = er[lane + i * 64];
    float4 b = hr[lane + i * 64];
    s += a.x * b.x + a.y * b.y + a.z * b.z + a.w * b.w;
  }
#pragma unroll
  for (int d = 1; d < 64; d <<= 1) s += __shfl_xor(s, d);
  if (lane == 0) out[v] = s;
}

// ---------------- silu(g)*u from stacked g13 ----------------
__global__ __launch_bounds__(256) void silu_k(const f16* __restrict__ g13,
                                              f16* __restrict__ t) {
  int c = blockIdx.x * 256 + threadIdx.x;  // 0..2815
  int s = blockIdx.y;
  float g = (float)g13[(size_t)s * (2 * HIDD) + c];
  float u = (float)g13[(size_t)s * (2 * HIDD) + HIDD + c];
  float r = g / (1.f + __expf(-g)) * u;
  t[(size_t)s * HIDD + c] = (f16)r;
}

// ---------------- V transpose: vT[c][s] = qkv[s][2048+c] ----------------
__global__ __launch_bounds__(256) void transpose_v(const f16* __restrict__ qkv,
                                                   f16* __restrict__ vT) {
  __shared__ f16 tile[32][34];
  int bs = blockIdx.x * 32;
  int bc = blockIdx.y * 32;
  int tx = threadIdx.x & 31, ty = threadIdx.x >> 5;
#pragma unroll
  for (int i = ty; i < 32; i += 8)
    tile[i][tx] = qkv[(size_t)(bs + i) * 3072 + 2048 + bc + tx];
  __syncthreads();
#pragma unroll
  for (int i = ty; i < 32; i += 8)
    vT[(size_t)(bc + i) * SEQ + bs + tx] = tile[tx][i];
}

// ---------------- GEMM: C(MxN) = A(MxK) . B(NxK)^T, fp16 in, MFMA ----------
// EPI 0: write fp16 C.  EPI 1: C_f32 += acc (residual add).
template <int EPI>
__global__ __launch_bounds__(256) void gemm_bt(const f16* __restrict__ A,
                                               const f16* __restrict__ B,
                                               void* __restrict__ Cout, int M,
                                               int N, int K) {
  __shared__ __align__(16) f16 As[128 * 32];
  __shared__ __align__(16) f16 Bs[128 * 32];
  const int t = threadIdx.x;
  const int lane = t & 63;
  const int wave = t >> 6;
  const int wr = wave >> 1, wc = wave & 1;
  const int bm = blockIdx.x, bn = blockIdx.y;
  const int lr = lane & 15, lk = lane >> 4;

  const int srow = t >> 2;
  const int scol = (t & 3) * 8;
  const f16* gA = A + (size_t)(bm * 128 + srow) * K + scol;
  const f16* gB = B + (size_t)(bn * 128 + srow) * K + scol;
  f16* lA = As + t * 8;
  f16* lB = Bs + t * 8;

  f4_t acc[4][4];
#pragma unroll
  for (int m = 0; m < 4; m++)
#pragma unroll
    for (int n = 0; n < 4; n++) acc[m][n] = {0.f, 0.f, 0.f, 0.f};

  for (int k0 = 0; k0 < K; k0 += 32) {
    __syncthreads();  // previous iteration's LDS reads complete
    async16(lA, gA + k0);
    async16(lA + 64 * 32, gA + (size_t)64 * K + k0);
    async16(lB, gB + k0);
    async16(lB + 64 * 32, gB + (size_t)64 * K + k0);
    __syncthreads();  // drains vmcnt before reads
    h8_t af[4], bfr[4];
#pragma unroll
    for (int m = 0; m < 4; m++)
      af[m] = *(const h8_t*)(As + (wr * 64 + m * 16 + lr) * 32 + lk * 8);
#pragma unroll
    for (int n = 0; n < 4; n++)
      bfr[n] = *(const h8_t*)(Bs + (wc * 64 + n * 16 + lr) * 32 + lk * 8);
#pragma unroll
    for (int m = 0; m < 4; m++)
#pragma unroll
      for (int n = 0; n < 4; n++) acc[m][n] = MFMA(af[m], bfr[n], acc[m][n]);
  }

  const int orow = bm * 128 + wr * 64 + lk * 4;
  const int ocol = bn * 128 + wc * 64 + lr;
#pragma unroll
  for (int m = 0; m < 4; m++)
#pragma unroll
    for (int n = 0; n < 4; n++)
#pragma unroll
      for (int j = 0; j < 4; j++) {
        int r = orow + m * 16 + j;
        int c = ocol + n * 16;
        if (EPI == 0) {
          ((f16*)Cout)[(size_t)r * N + c] = (f16)acc[m][n][j];
        } else {
          float* pC = (float*)Cout + (size_t)r * N + c;
          *pC += acc[m][n][j];
        }
      }
}

// ------- deep-pipelined GEMM: 128x256 tile, BK=64, 8 waves, dbuf LDS -------
// C(MxN) = A(MxK).B(NxK)^T, fp16 out. Fragment-major LDS (conflict-free):
// A slot s=mblk*2+ks (16 slots x 1KB), lane l holds row mblk*16+(l&15),
// k = ks*32+(l>>4)*8 at byte offset s*1024 + l*16.  B: 32 slots.
// Counted vmcnt(6): tile t+1's 6 loads stay in flight across barriers.
__global__ __launch_bounds__(512, 2) void gemm8(const f16* __restrict__ A,
                                                const f16* __restrict__ B,
                                                f16* __restrict__ C, int MB,
                                                int N, int K) {
  __shared__ __align__(16) f16 lds[2][24576];  // per buf: A 8192, B 16384 f16
  const int tid = threadIdx.x;
  const int l = tid & 63;
  const int w = tid >> 6;         // 0..7
  const int wr = w >> 2;          // 0..1  (M half)
  const int wc = w & 3;           // 0..3  (N quarter)
  const int lr = l & 15, lk = l >> 4;

  // XCD-bijective swizzle (grid % 8 == 0 guaranteed by caller)
  const int nwg = gridDim.x;
  const int cpx = nwg >> 3;
  const int id = blockIdx.x;
  const int swz = (id & 7) * cpx + (id >> 3);
  const int bm = swz % MB;
  const int bn = swz / MB;

  const int nt = K >> 6;  // BK=64 tiles

  // staging source rows (lane-invariant parts precomputed)
  // A slots: w*2 + c (c=0,1) ; B slots: w*4 + c (c=0..3)
  const f16* gA0 = A + (size_t)(bm * 128 + (w * 2 + 0) / 2 * 16 + lr) * K;
  const f16* gA1 = A + (size_t)(bm * 128 + (w * 2 + 1) / 2 * 16 + lr) * K;
  const f16* gB0 = B + (size_t)(bn * 256 + (w * 4 + 0) / 2 * 16 + lr) * K;
  const f16* gB1 = B + (size_t)(bn * 256 + (w * 4 + 1) / 2 * 16 + lr) * K;
  const f16* gB2 = B + (size_t)(bn * 256 + (w * 4 + 2) / 2 * 16 + lr) * K;
  const f16* gB3 = B + (size_t)(bn * 256 + (w * 4 + 3) / 2 * 16 + lr) * K;
  const int kA0 = ((w * 2 + 0) & 1) * 32 + lk * 8;
  const int kA1 = ((w * 2 + 1) & 1) * 32 + lk * 8;
  const int kB0 = ((w * 4 + 0) & 1) * 32 + lk * 8;
  const int kB1 = ((w * 4 + 1) & 1) * 32 + lk * 8;
  const int kB2 = ((w * 4 + 2) & 1) * 32 + lk * 8;
  const int kB3 = ((w * 4 + 3) & 1) * 32 + lk * 8;

#define STAGE(tt, bb)                                                      \
  {                                                                        \
    const int k0_ = (tt) * 64;                                             \
    f16* lb = &lds[bb][0];                                                 \
    async16(lb + (w * 2 + 0) * 512 + l * 8, gA0 + k0_ + kA0);              \
    async16(lb + (w * 2 + 1) * 512 + l * 8, gA1 + k0_ + kA1);              \
    async16(lb + 8192 + (w * 4 + 0) * 512 + l * 8, gB0 + k0_ + kB0);       \
    async16(lb + 8192 + (w * 4 + 1) * 512 + l * 8, gB1 + k0_ + kB1);       \
    async16(lb + 8192 + (w * 4 + 2) * 512 + l * 8, gB2 + k0_ + kB2);       \
    async16(lb + 8192 + (w * 4 + 3) * 512 + l * 8, gB3 + k0_ + kB3);       \
  }

  f4_t acc[4][4];
#pragma unroll
  for (int m = 0; m < 4; m++)
#pragma unroll
    for (int n = 0; n < 4; n++) acc[m][n] = {0.f, 0.f, 0.f, 0.f};

  STAGE(0, 0);
  STAGE(1, 1);

  for (int t = 0; t < nt; ++t) {
    const int buf = t & 1;
    asm volatile("s_waitcnt vmcnt(6)" ::: "memory");
    __builtin_amdgcn_s_barrier();  // tile t visible to all waves
    h8_t af[4][2], bf[4][2];
#pragma unroll
    for (int m = 0; m < 4; m++)
#pragma unroll
      for (int ks = 0; ks < 2; ks++)
        af[m][ks] =
            *(const h8_t*)(&lds[buf][((wr * 4 + m) * 2 + ks) * 512 + l * 8]);
#pragma unroll
    for (int n = 0; n < 4; n++)
#pragma unroll
      for (int ks = 0; ks < 2; ks++)
        bf[n][ks] = *(const h8_t*)(&lds[buf][8192 +
                                            ((wc * 4 + n) * 2 + ks) * 512 +
                                            l * 8]);
    asm volatile("s_waitcnt lgkmcnt(0)" ::: "memory");
    __builtin_amdgcn_sched_barrier(0);
    __builtin_amdgcn_s_barrier();  // all reads done; safe to overwrite buf
    const int tn = (t + 2 < nt) ? (t + 2) : (t + 2 - nt);  // dummy at tail
    STAGE(tn, buf);
    __builtin_amdgcn_s_setprio(1);
#pragma unroll
    for (int ks = 0; ks < 2; ks++)
#pragma unroll
      for (int m = 0; m < 4; m++)
#pragma unroll
        for (int n = 0; n < 4; n++)
          acc[m][n] = MFMA(af[m][ks], bf[n][ks], acc[m][n]);
    __builtin_amdgcn_s_setprio(0);
  }

  const int orow = bm * 128 + wr * 64 + lk * 4;
  const int ocol = bn * 256 + wc * 64 + lr;
#pragma unroll
  for (int m = 0; m < 4; m++)
#pragma unroll
    for (int n = 0; n < 4; n++)
#pragma unroll
      for (int j = 0; j < 4; j++)
        C[(size_t)(orow + m * 16 + j) * N + ocol + n * 16] = (f16)acc[m][n][j];
#undef STAGE
}

// ---------------- flash attention, KV-split across 4 waves ------------
// Block: 4 waves, (head, 32 q-rows). Wave w does K-tiles w, w+4, ...;
// private (m,l,oacc) partials; LSE-merge at the end via LDS.
// Heavy-first: qb reversed so long causal blocks launch first.
__global__ __launch_bounds__(256) void attn_k(const f16* __restrict__ qkv,
                                              const f16* __restrict__ vT,
                                              f16* __restrict__ o) {
  const int hh = blockIdx.y;
  const int qb = (gridDim.x - 1) - blockIdx.x;  // heavy-first
  const int tid = threadIdx.x;
  const int wave = tid >> 6;
  const int lane = tid & 63;
  const int lr = lane & 15, lk = lane >> 4;
  const int q0 = qb * 32;
  __shared__ __align__(16) char P[4][4096];  // per-wave P, XOR-swizzled
  __shared__ float MB[3][64][48];            // waves 1..3 partials

  h8_t qf[2][2];
#pragma unroll
  for (int m = 0; m < 2; m++)
#pragma unroll
    for (int ks = 0; ks < 2; ks++)
      qf[m][ks] = *(const h8_t*)(qkv + (size_t)(q0 + m * 16 + lr) * 3072 +
                                 hh * 64 + ks * 32 + lk * 8);

  float mrow[2][4], lsum[2][4];
  f4_t oacc[2][4];
#pragma unroll
  for (int m = 0; m < 2; m++)
#pragma unroll
    for (int j = 0; j < 4; j++) {
      mrow[m][j] = -1e30f;
      lsum[m][j] = 0.f;
    }
#pragma unroll
  for (int m = 0; m < 2; m++)
#pragma unroll
    for (int n = 0; n < 4; n++) oacc[m][n] = {0.f, 0.f, 0.f, 0.f};

  const int ntiles = (qb >> 1) + 1;
  char* Pw = P[wave];
  for (int kt = wave; kt < ntiles; kt += 4) {
    f4_t sacc[2][4];
#pragma unroll
    for (int m = 0; m < 2; m++)
#pragma unroll
      for (int n = 0; n < 4; n++) sacc[m][n] = {0.f, 0.f, 0.f, 0.f};
    __builtin_amdgcn_s_setprio(1);
#pragma unroll
    for (int ks = 0; ks < 2; ks++) {
      h8_t kf[4];
#pragma unroll
      for (int n = 0; n < 4; n++)
        kf[n] = *(const h8_t*)(qkv + (size_t)(kt * 64 + n * 16 + lr) * 3072 +
                               1024 + hh * 64 + ks * 32 + lk * 8);
#pragma unroll
      for (int m = 0; m < 2; m++)
#pragma unroll
        for (int n = 0; n < 4; n++)
          sacc[m][n] = MFMA(qf[m][ks], kf[n], sacc[m][n]);
    }
    __builtin_amdgcn_s_setprio(0);
    const bool lastt = (kt == ntiles - 1);
    float pv[2][4][4];
#pragma unroll
    for (int m = 0; m < 2; m++)
#pragma unroll
      for (int n = 0; n < 4; n++)
#pragma unroll
        for (int j = 0; j < 4; j++) {
          float sv = sacc[m][n][j] * 0.125f;
          if (lastt && (kt * 64 + n * 16 + lr) > (q0 + m * 16 + lk * 4 + j))
            sv = -1e30f;
          pv[m][n][j] = sv;
        }
    // online softmax (rows live on 16 lanes sharing lk)
#pragma unroll
    for (int m = 0; m < 2; m++)
#pragma unroll
      for (int j = 0; j < 4; j++) {
        float mx = fmaxf(fmaxf(pv[m][0][j], pv[m][1][j]),
                         fmaxf(pv[m][2][j], pv[m][3][j]));
#pragma unroll
        for (int d = 1; d < 16; d <<= 1) mx = fmaxf(mx, __shfl_xor(mx, d));
        float mnew = fmaxf(mrow[m][j], mx);
        float corr = __expf(mrow[m][j] - mnew);
        mrow[m][j] = mnew;
        float rs = 0.f;
#pragma unroll
        for (int n = 0; n < 4; n++) {
          float pe = __expf(pv[m][n][j] - mnew);
          pv[m][n][j] = pe;
          rs += pe;
        }
#pragma unroll
        for (int d = 1; d < 16; d <<= 1) rs += __shfl_xor(rs, d);
        lsum[m][j] = lsum[m][j] * corr + rs;
#pragma unroll
        for (int n = 0; n < 4; n++) oacc[m][n][j] *= corr;
      }
    // P round-trip: per-wave private LDS, same-wave DS ops are ordered.
#pragma unroll
    for (int m = 0; m < 2; m++)
#pragma unroll
      for (int n = 0; n < 4; n++)
#pragma unroll
        for (int j = 0; j < 4; j++) {
          int r = m * 16 + lk * 4 + j, c = n * 16 + lr;
          int off = (r * 128 + c * 2) ^ ((r & 7) << 4);
          *(f16*)(Pw + off) = (f16)pv[m][n][j];
        }
    __builtin_amdgcn_s_setprio(1);
#pragma unroll
    for (int ks = 0; ks < 2; ks++) {
      h8_t pf[2], vf[4];
#pragma unroll
      for (int m = 0; m < 2; m++) {
        int r = m * 16 + lr;
        int off = (r * 128 + ks * 64 + lk * 16) ^ ((r & 7) << 4);
        pf[m] = *(const h8_t*)(Pw + off);
      }
#pragma unroll
      for (int n = 0; n < 4; n++)
        vf[n] = *(const h8_t*)(vT + (size_t)(hh * 64 + n * 16 + lr) * SEQ +
                               kt * 64 + ks * 32 + lk * 8);
#pragma unroll
      for (int m = 0; m < 2; m++)
#pragma unroll
        for (int n = 0; n < 4; n++)
          oacc[m][n] = MFMA(pf[m], vf[n], oacc[m][n]);
    }
    __builtin_amdgcn_s_setprio(0);
  }

  // ---- cross-wave LSE merge ----
  if (wave > 0) {
    float* d = &MB[wave - 1][lane][0];
#pragma unroll
    for (int m = 0; m < 2; m++)
#pragma unroll
      for (int j = 0; j < 4; j++) {
        d[m * 4 + j] = mrow[m][j];
        d[8 + m * 4 + j] = lsum[m][j];
      }
#pragma unroll
    for (int m = 0; m < 2; m++)
#pragma unroll
      for (int n = 0; n < 4; n++)
#pragma unroll
        for (int j = 0; j < 4; j++)
          d[16 + m * 16 + n * 4 + j] = oacc[m][n][j];
  }
  __syncthreads();
  if (wave == 0) {
#pragma unroll
    for (int m = 0; m < 2; m++)
#pragma unroll
      for (int j = 0; j < 4; j++) {
        float M = mrow[m][j];
#pragma unroll
        for (int w = 0; w < 3; w++) M = fmaxf(M, MB[w][lane][m * 4 + j]);
        float sc0 = __expf(mrow[m][j] - M);
        float L = lsum[m][j] * sc0;
        float scw[3];
#pragma unroll
        for (int w = 0; w < 3; w++) {
          scw[w] = __expf(MB[w][lane][m * 4 + j] - M);
          L += MB[w][lane][8 + m * 4 + j] * scw[w];
        }
        float invL = 1.f / L;
#pragma unroll
        for (int n = 0; n < 4; n++) {
          float val = oacc[m][n][j] * sc0;
#pragma unroll
          for (int w = 0; w < 3; w++)
            val += MB[w][lane][16 + m * 16 + n * 4 + j] * scw[w];
          o[(size_t)(q0 + m * 16 + lk * 4 + j) * DIM + hh * 64 + n * 16 + lr] =
              (f16)(val * invL);
        }
      }
  }
}

extern "C" void kernel_launch(void* const* d_in, const int* in_sizes, int n_in,
                              void* d_out, int out_size, void* d_ws,
                              size_t ws_size, hipStream_t stream) {
  (void)in_sizes; (void)n_in; (void)out_size; (void)ws_size;
  const int* tokens = (const int*)d_in[0];
  const float* emb = (const float*)d_in[1];
  const float* wq = (const float*)d_in[2];
  const float* wk = (const float*)d_in[3];
  const float* wv = (const float*)d_in[4];
  const float* wo = (const float*)d_in[5];
  const float* w1 = (const float*)d_in[6];
  const float* w2 = (const float*)d_in[7];
  const float* w3 = (const float*)d_in[8];
  const float* anw = (const float*)d_in[9];
  const float* fnw = (const float*)d_in[10];
  const float* finw = (const float*)d_in[11];
  float* out = (float*)d_out;

  char* p = (char*)d_ws;
  auto alloc = [&](size_t bytes) {
    char* r = p;
    p += (bytes + 255) & ~(size_t)255;
    return r;
  };
  f16* wqkv_l = (f16*)alloc((size_t)3 * DIM * DIM * 2);
  f16* wo_l = (f16*)alloc((size_t)DIM * DIM * 2);
  f16* w13_l = (f16*)alloc((size_t)2 * HIDD * DIM * 2);
  f16* w2_l = (f16*)alloc((size_t)DIM * HIDD * 2);
  float* hbuf = (float*)alloc((size_t)SEQ * DIM * 4);
  f16* x_h = (f16*)alloc((size_t)SEQ * DIM * 2);
  f16* qkv_h = (f16*)alloc((size_t)SEQ * 3 * DIM * 2);
  f16* vT_h = (f16*)alloc((size_t)DIM * SEQ * 2);
  f16* o_h = (f16*)alloc((size_t)SEQ * DIM * 2);
  f16* g13_h = (f16*)alloc((size_t)SEQ * 2 * HIDD * 2);
  f16* t_h = (f16*)alloc((size_t)SEQ * HIDD * 2);
  float* tab = (float*)alloc((size_t)SEQ * 32 * 2 * 4);
  float* hn = (float*)alloc(4096);

  embed_k<<<SEQ, 256, 0, stream>>>(tokens, emb, hbuf);
  rope_tab_k<<<(SEQ * 32 + 255) / 256, 256, 0, stream>>>(tab);

  const int CAST_BLOCKS = (4 * (DIM * DIM / 4) + 3 * (HIDD * DIM / 4)) / 256;
  for (int l = 0; l < LNUM; l++) {
    const size_t offDD = (size_t)l * DIM * DIM;
    const size_t offHD = (size_t)l * HIDD * DIM;
    cast_layer_k<<<CAST_BLOCKS, 256, 0, stream>>>(
        wq + offDD, wk + offDD, wv + offDD, wo + offDD, w1 + offHD,
        w3 + offHD, w2 + offHD, wqkv_l, wo_l, w13_l, w2_l);

    rmsnorm_k<<<SEQ, 256, 0, stream>>>(hbuf, anw + (size_t)l * DIM, x_h);
    {
      // 128x256 tile deep-pipeline: grid = (2048/128)*(3072/256) = 16*12
      gemm8<<<16 * 12, 512, 0, stream>>>(x_h, wqkv_l, qkv_h, 16, 3 * DIM, DIM);
    }
    rope_k<<<(SEQ * 2 * NH * 32) / 256, 256, 0, stream>>>(qkv_h, tab);
    {
      dim3 g(SEQ / 32, DIM / 32);
      transpose_v<<<g, 256, 0, stream>>>(qkv_h, vT_h);
    }
    {
      dim3 g(SEQ / 32, NH);
      attn_k<<<g, 256, 0, stream>>>(qkv_h, vT_h, o_h);
    }
    {
      dim3 g(SEQ / 128, DIM / 128);
      gemm_bt<1><<<g, 256, 0, stream>>>(o_h, wo_l, hbuf, SEQ, DIM, DIM);
    }
    rmsnorm_k<<<SEQ, 256, 0, stream>>>(hbuf, fnw + (size_t)l * DIM, x_h);
    {
      // grid = (2048/128)*(5632/256) = 16*22
      gemm8<<<16 * 22, 512, 0, stream>>>(x_h, w13_l, g13_h, 16, 2 * HIDD, DIM);
    }
    {
      dim3 g(HIDD / 256, SEQ);
      silu_k<<<g, 256, 0, stream>>>(g13_h, t_h);
    }
    {
      dim3 g(SEQ / 128, DIM / 128);
      gemm_bt<1><<<g, 256, 0, stream>>>(t_h, w2_l, hbuf, SEQ, DIM, HIDD);
    }
  }
  final_norm_k<<<1, 256, 0, stream>>>(hbuf, finw, hn);
  logits_k<<<VOCAB / 4, 256, 0, stream>>>(hn, emb, out);
}

// Round 4
// 1143.128 us; speedup vs baseline: 1.1030x; 1.1030x over previous
//
#include <hip/hip_runtime.h>

#define LNUM 4
#define DIM 1024
#define NH 16
#define VOCAB 32000
#define SEQ 2048
#define HIDD 2816

typedef _Float16 f16;
typedef _Float16 h8_t __attribute__((ext_vector_type(8)));
typedef _Float16 h4_t __attribute__((ext_vector_type(4)));
typedef float f4_t __attribute__((ext_vector_type(4)));

#define MFMA(a, b, c) __builtin_amdgcn_mfma_f32_16x16x32_f16(a, b, c, 0, 0, 0)

__device__ __forceinline__ void async16(void* lds, const void* g) {
  __builtin_amdgcn_global_load_lds(
      (const __attribute__((address_space(1))) void*)g,
      (__attribute__((address_space(3))) void*)lds, 16, 0, 0);
}

// DPP row_ror butterfly primitives (16-lane rows; pure VALU, no LDS)
template <int N>
__device__ __forceinline__ float ror16(float x) {
  int r = __builtin_amdgcn_update_dpp(0, __builtin_bit_cast(int, x),
                                      0x120 | N, 0xF, 0xF, true);
  return __builtin_bit_cast(float, r);
}
__device__ __forceinline__ float rmax16(float v) {
  v = fmaxf(v, ror16<1>(v));
  v = fmaxf(v, ror16<2>(v));
  v = fmaxf(v, ror16<4>(v));
  v = fmaxf(v, ror16<8>(v));
  return v;
}
__device__ __forceinline__ float rsum16(float v) {
  v += ror16<1>(v);
  v += ror16<2>(v);
  v += ror16<4>(v);
  v += ror16<8>(v);
  return v;
}

// ---------------- fused per-layer fp32 -> fp16 weight cast ----------------
__global__ __launch_bounds__(256) void cast_layer_k(
    const float* __restrict__ wq, const float* __restrict__ wk,
    const float* __restrict__ wv, const float* __restrict__ wo,
    const float* __restrict__ w1, const float* __restrict__ w3,
    const float* __restrict__ w2, f16* __restrict__ wqkv,
    f16* __restrict__ wod, f16* __restrict__ w13, f16* __restrict__ w2d) {
  const int DD4c = DIM * DIM / 4, HD4c = HIDD * DIM / 4;
  int i = blockIdx.x * 256 + threadIdx.x;  // total 4*DD4c + 3*HD4c = 3211264
  const float* s;
  f16* d;
  int si, di;
  if (i < 3 * DD4c) {
    d = wqkv;
    di = i;
    if (i < DD4c) {
      s = wq; si = i;
    } else if (i < 2 * DD4c) {
      s = wk; si = i - DD4c;
    } else {
      s = wv; si = i - 2 * DD4c;
    }
  } else if (i < 4 * DD4c) {
    s = wo; si = i - 3 * DD4c; d = wod; di = si;
  } else if (i < 4 * DD4c + HD4c) {
    s = w1; si = i - 4 * DD4c; d = w13; di = si;
  } else if (i < 4 * DD4c + 2 * HD4c) {
    s = w3; si = i - 4 * DD4c - HD4c; d = w13; di = si + HD4c;
  } else {
    s = w2; si = i - 4 * DD4c - 2 * HD4c; d = w2d; di = si;
  }
  float4 v = ((const float4*)s)[si];
  ((h4_t*)d)[di] = (h4_t){(f16)v.x, (f16)v.y, (f16)v.z, (f16)v.w};
}

// ---------------- embedding gather ----------------
__global__ __launch_bounds__(256) void embed_k(const int* __restrict__ tok,
                                               const float* __restrict__ emb,
                                               float* __restrict__ h) {
  const int s = blockIdx.x, t = threadIdx.x;
  ((float4*)(h + (size_t)s * DIM))[t] =
      ((const float4*)(emb + (size_t)tok[s] * DIM))[t];
}

// ---------------- rope table (cos,sin per (s,f)) ----------------
__global__ void rope_tab_k(float* __restrict__ tab) {
  int i = blockIdx.x * 256 + threadIdx.x;
  if (i >= SEQ * 32) return;
  int s = i >> 5, f = i & 31;
  float inv = powf(10000.f, -(float)f * (1.f / 32.f));
  float a = (float)s * inv;
  float sn, c;
  sincosf(a, &sn, &c);
  tab[i * 2] = c;
  tab[i * 2 + 1] = sn;
}

// ---------------- rope apply in-place on q,k parts of qkv ----------------
__global__ __launch_bounds__(256) void rope_k(f16* __restrict__ qkv,
                                              const float* __restrict__ tab) {
  int i = blockIdx.x * 256 + threadIdx.x;  // SEQ*2*NH*32 = 2M
  int f = i & 31, hh = (i >> 5) & 15, part = (i >> 9) & 1, s = i >> 10;
  size_t base = (size_t)s * 3072 + part * 1024 + hh * 64 + f * 2;
  float xr = (float)qkv[base], xi = (float)qkv[base + 1];
  float c = tab[(s * 32 + f) * 2], sn = tab[(s * 32 + f) * 2 + 1];
  qkv[base] = (f16)(xr * c - xi * sn);
  qkv[base + 1] = (f16)(xr * sn + xi * c);
}

// ---------------- rmsnorm: fp32 h row -> fp16 out ----------------
__global__ __launch_bounds__(256) void rmsnorm_k(const float* __restrict__ h,
                                                 const float* __restrict__ w,
                                                 f16* __restrict__ out) {
  const int s = blockIdx.x, t = threadIdx.x;
  float4 v = ((const float4*)(h + (size_t)s * DIM))[t];
  float ss = v.x * v.x + v.y * v.y + v.z * v.z + v.w * v.w;
#pragma unroll
  for (int d = 1; d < 64; d <<= 1) ss += __shfl_xor(ss, d);
  __shared__ float red[4];
  if ((t & 63) == 0) red[t >> 6] = ss;
  __syncthreads();
  float tot = red[0] + red[1] + red[2] + red[3];
  float sc = rsqrtf(tot * (1.f / (float)DIM) + 1e-5f);
  float4 wv = ((const float4*)w)[t];
  ((h4_t*)(out + (size_t)s * DIM))[t] =
      (h4_t){(f16)(v.x * sc * wv.x), (f16)(v.y * sc * wv.y),
             (f16)(v.z * sc * wv.z), (f16)(v.w * sc * wv.w)};
}

// ---------------- final rmsnorm (row SEQ-1) -> fp32 ----------------
__global__ __launch_bounds__(256) void final_norm_k(const float* __restrict__ h,
                                                    const float* __restrict__ w,
                                                    float* __restrict__ hn) {
  const int t = threadIdx.x;
  float4 v = ((const float4*)(h + (size_t)(SEQ - 1) * DIM))[t];
  float ss = v.x * v.x + v.y * v.y + v.z * v.z + v.w * v.w;
#pragma unroll
  for (int d = 1; d < 64; d <<= 1) ss += __shfl_xor(ss, d);
  __shared__ float red[4];
  if ((t & 63) == 0) red[t >> 6] = ss;
  __syncthreads();
  float tot = red[0] + red[1] + red[2] + red[3];
  float sc = rsqrtf(tot * (1.f / (float)DIM) + 1e-5f);
  float4 wv = ((const float4*)w)[t];
  ((float4*)hn)[t] = make_float4(v.x * sc * wv.x, v.y * sc * wv.y,
                                 v.z * sc * wv.z, v.w * sc * wv.w);
}

// ---------------- logits: out[v] = hn . emb[v] (fp32) ----------------
__global__ __launch_bounds__(256) void logits_k(const float* __restrict__ hn,
                                                const float* __restrict__ emb,
                                                float* __restrict__ out) {
  const int v = blockIdx.x * 4 + (threadIdx.x >> 6);
  const int lane = threadIdx.x & 63;
  const float4* er = (const float4*)(emb + (size_t)v * DIM);
  const float4* hr = (const float4*)hn;
  float s = 0.f;
#pragma unroll
  for (int i = 0; i < 4; i++) {
    float4 a = er[lane + i * 64];
    float4 b = hr[lane + i * 64];
    s += a.x * b.x + a.y * b.y + a.z * b.z + a.w * b.w;
  }
#pragma unroll
  for (int d = 1; d < 64; d <<= 1) s += __shfl_xor(s, d);
  if (lane == 0) out[v] = s;
}

// ---------------- silu(g)*u from stacked g13 ----------------
__global__ __launch_bounds__(256) void silu_k(const f16* __restrict__ g13,
                                              f16* __restrict__ t) {
  int c = blockIdx.x * 256 + threadIdx.x;  // 0..2815
  int s = blockIdx.y;
  float g = (float)g13[(size_t)s * (2 * HIDD) + c];
  float u = (float)g13[(size_t)s * (2 * HIDD) + HIDD + c];
  float r = g / (1.f + __expf(-g)) * u;
  t[(size_t)s * HIDD + c] = (f16)r;
}

// ---------------- V transpose: vT[c][s] = qkv[s][2048+c] ----------------
__global__ __launch_bounds__(256) void transpose_v(const f16* __restrict__ qkv,
                                                   f16* __restrict__ vT) {
  __shared__ f16 tile[32][34];
  int bs = blockIdx.x * 32;
  int bc = blockIdx.y * 32;
  int tx = threadIdx.x & 31, ty = threadIdx.x >> 5;
#pragma unroll
  for (int i = ty; i < 32; i += 8)
    tile[i][tx] = qkv[(size_t)(bs + i) * 3072 + 2048 + bc + tx];
  __syncthreads();
#pragma unroll
  for (int i = ty; i < 32; i += 8)
    vT[(size_t)(bc + i) * SEQ + bs + tx] = tile[tx][i];
}

// ---------------- GEMM: C(MxN) = A(MxK) . B(NxK)^T, fp16 in, MFMA ----------
// EPI 0: write fp16 C.  EPI 1: C_f32 += acc (residual add).
template <int EPI>
__global__ __launch_bounds__(256) void gemm_bt(const f16* __restrict__ A,
                                               const f16* __restrict__ B,
                                               void* __restrict__ Cout, int M,
                                               int N, int K) {
  __shared__ __align__(16) f16 As[128 * 32];
  __shared__ __align__(16) f16 Bs[128 * 32];
  const int t = threadIdx.x;
  const int lane = t & 63;
  const int wave = t >> 6;
  const int wr = wave >> 1, wc = wave & 1;
  const int bm = blockIdx.x, bn = blockIdx.y;
  const int lr = lane & 15, lk = lane >> 4;

  const int srow = t >> 2;
  const int scol = (t & 3) * 8;
  const f16* gA = A + (size_t)(bm * 128 + srow) * K + scol;
  const f16* gB = B + (size_t)(bn * 128 + srow) * K + scol;
  f16* lA = As + t * 8;
  f16* lB = Bs + t * 8;

  f4_t acc[4][4];
#pragma unroll
  for (int m = 0; m < 4; m++)
#pragma unroll
    for (int n = 0; n < 4; n++) acc[m][n] = {0.f, 0.f, 0.f, 0.f};

  for (int k0 = 0; k0 < K; k0 += 32) {
    __syncthreads();  // previous iteration's LDS reads complete
    async16(lA, gA + k0);
    async16(lA + 64 * 32, gA + (size_t)64 * K + k0);
    async16(lB, gB + k0);
    async16(lB + 64 * 32, gB + (size_t)64 * K + k0);
    __syncthreads();  // drains vmcnt before reads
    h8_t af[4], bfr[4];
#pragma unroll
    for (int m = 0; m < 4; m++)
      af[m] = *(const h8_t*)(As + (wr * 64 + m * 16 + lr) * 32 + lk * 8);
#pragma unroll
    for (int n = 0; n < 4; n++)
      bfr[n] = *(const h8_t*)(Bs + (wc * 64 + n * 16 + lr) * 32 + lk * 8);
#pragma unroll
    for (int m = 0; m < 4; m++)
#pragma unroll
      for (int n = 0; n < 4; n++) acc[m][n] = MFMA(af[m], bfr[n], acc[m][n]);
  }

  const int orow = bm * 128 + wr * 64 + lk * 4;
  const int ocol = bn * 128 + wc * 64 + lr;
#pragma unroll
  for (int m = 0; m < 4; m++)
#pragma unroll
    for (int n = 0; n < 4; n++)
#pragma unroll
      for (int j = 0; j < 4; j++) {
        int r = orow + m * 16 + j;
        int c = ocol + n * 16;
        if (EPI == 0) {
          ((f16*)Cout)[(size_t)r * N + c] = (f16)acc[m][n][j];
        } else {
          float* pC = (float*)Cout + (size_t)r * N + c;
          *pC += acc[m][n][j];
        }
      }
}

// ---------------- flash attention, KV-split across 4 waves ------------
// Block: 4 waves, (head, 32 q-rows). Wave w does K-tiles w, w+4, ...;
// private (m,l,oacc) partials; LSE-merge at the end via LDS.
// Softmax reductions use DPP row_ror butterflies (no LDS latency).
__global__ __launch_bounds__(256) void attn_k(const f16* __restrict__ qkv,
                                              const f16* __restrict__ vT,
                                              f16* __restrict__ o) {
  const int hh = blockIdx.y;
  const int qb = blockIdx.x;
  const int tid = threadIdx.x;
  const int wave = tid >> 6;
  const int lane = tid & 63;
  const int lr = lane & 15, lk = lane >> 4;
  const int q0 = qb * 32;
  __shared__ __align__(16) char P[4][4096];  // per-wave P, XOR-swizzled
  __shared__ float MB[3][64][48];            // waves 1..3 partials

  h8_t qf[2][2];
#pragma unroll
  for (int m = 0; m < 2; m++)
#pragma unroll
    for (int ks = 0; ks < 2; ks++)
      qf[m][ks] = *(const h8_t*)(qkv + (size_t)(q0 + m * 16 + lr) * 3072 +
                                 hh * 64 + ks * 32 + lk * 8);

  float mrow[2][4], lsum[2][4];
  f4_t oacc[2][4];
#pragma unroll
  for (int m = 0; m < 2; m++)
#pragma unroll
    for (int j = 0; j < 4; j++) {
      mrow[m][j] = -1e30f;
      lsum[m][j] = 0.f;
    }
#pragma unroll
  for (int m = 0; m < 2; m++)
#pragma unroll
    for (int n = 0; n < 4; n++) oacc[m][n] = {0.f, 0.f, 0.f, 0.f};

  const int ntiles = (qb >> 1) + 1;
  char* Pw = P[wave];
  for (int kt = wave; kt < ntiles; kt += 4) {
    f4_t sacc[2][4];
#pragma unroll
    for (int m = 0; m < 2; m++)
#pragma unroll
      for (int n = 0; n < 4; n++) sacc[m][n] = {0.f, 0.f, 0.f, 0.f};
#pragma unroll
    for (int ks = 0; ks < 2; ks++) {
      h8_t kf[4];
#pragma unroll
      for (int n = 0; n < 4; n++)
        kf[n] = *(const h8_t*)(qkv + (size_t)(kt * 64 + n * 16 + lr) * 3072 +
                               1024 + hh * 64 + ks * 32 + lk * 8);
#pragma unroll
      for (int m = 0; m < 2; m++)
#pragma unroll
        for (int n = 0; n < 4; n++)
          sacc[m][n] = MFMA(qf[m][ks], kf[n], sacc[m][n]);
    }
    const bool lastt = (kt == ntiles - 1);
    float pv[2][4][4];
#pragma unroll
    for (int m = 0; m < 2; m++)
#pragma unroll
      for (int n = 0; n < 4; n++)
#pragma unroll
        for (int j = 0; j < 4; j++) {
          float sv = sacc[m][n][j] * 0.125f;
          if (lastt && (kt * 64 + n * 16 + lr) > (q0 + m * 16 + lk * 4 + j))
            sv = -1e30f;
          pv[m][n][j] = sv;
        }
    // online softmax (rows live on 16 lanes sharing lk) — DPP reductions
#pragma unroll
    for (int m = 0; m < 2; m++)
#pragma unroll
      for (int j = 0; j < 4; j++) {
        float mx = fmaxf(fmaxf(pv[m][0][j], pv[m][1][j]),
                         fmaxf(pv[m][2][j], pv[m][3][j]));
        mx = rmax16(mx);
        float mnew = fmaxf(mrow[m][j], mx);
        float corr = __expf(mrow[m][j] - mnew);
        mrow[m][j] = mnew;
        float rs = 0.f;
#pragma unroll
        for (int n = 0; n < 4; n++) {
          float pe = __expf(pv[m][n][j] - mnew);
          pv[m][n][j] = pe;
          rs += pe;
        }
        rs = rsum16(rs);
        lsum[m][j] = lsum[m][j] * corr + rs;
#pragma unroll
        for (int n = 0; n < 4; n++) oacc[m][n][j] *= corr;
      }
    // P round-trip: per-wave private LDS, same-wave DS ops are ordered.
#pragma unroll
    for (int m = 0; m < 2; m++)
#pragma unroll
      for (int n = 0; n < 4; n++)
#pragma unroll
        for (int j = 0; j < 4; j++) {
          int r = m * 16 + lk * 4 + j, c = n * 16 + lr;
          int off = (r * 128 + c * 2) ^ ((r & 7) << 4);
          *(f16*)(Pw + off) = (f16)pv[m][n][j];
        }
#pragma unroll
    for (int ks = 0; ks < 2; ks++) {
      h8_t pf[2], vf[4];
#pragma unroll
      for (int m = 0; m < 2; m++) {
        int r = m * 16 + lr;
        int off = (r * 128 + ks * 64 + lk * 16) ^ ((r & 7) << 4);
        pf[m] = *(const h8_t*)(Pw + off);
      }
#pragma unroll
      for (int n = 0; n < 4; n++)
        vf[n] = *(const h8_t*)(vT + (size_t)(hh * 64 + n * 16 + lr) * SEQ +
                               kt * 64 + ks * 32 + lk * 8);
#pragma unroll
      for (int m = 0; m < 2; m++)
#pragma unroll
        for (int n = 0; n < 4; n++)
          oacc[m][n] = MFMA(pf[m], vf[n], oacc[m][n]);
    }
  }

  // ---- cross-wave LSE merge ----
  if (wave > 0) {
    float* d = &MB[wave - 1][lane][0];
#pragma unroll
    for (int m = 0; m < 2; m++)
#pragma unroll
      for (int j = 0; j < 4; j++) {
        d[m * 4 + j] = mrow[m][j];
        d[8 + m * 4 + j] = lsum[m][j];
      }
#pragma unroll
    for (int m = 0; m < 2; m++)
#pragma unroll
      for (int n = 0; n < 4; n++)
#pragma unroll
        for (int j = 0; j < 4; j++)
          d[16 + m * 16 + n * 4 + j] = oacc[m][n][j];
  }
  __syncthreads();
  if (wave == 0) {
#pragma unroll
    for (int m = 0; m < 2; m++)
#pragma unroll
      for (int j = 0; j < 4; j++) {
        float M = mrow[m][j];
#pragma unroll
        for (int w = 0; w < 3; w++) M = fmaxf(M, MB[w][lane][m * 4 + j]);
        float sc0 = __expf(mrow[m][j] - M);
        float L = lsum[m][j] * sc0;
        float scw[3];
#pragma unroll
        for (int w = 0; w < 3; w++) {
          scw[w] = __expf(MB[w][lane][m * 4 + j] - M);
          L += MB[w][lane][8 + m * 4 + j] * scw[w];
        }
        float invL = 1.f / L;
#pragma unroll
        for (int n = 0; n < 4; n++) {
          float val = oacc[m][n][j] * sc0;
#pragma unroll
          for (int w = 0; w < 3; w++)
            val += MB[w][lane][16 + m * 16 + n * 4 + j] * scw[w];
          o[(size_t)(q0 + m * 16 + lk * 4 + j) * DIM + hh * 64 + n * 16 + lr] =
              (f16)(val * invL);
        }
      }
  }
}

extern "C" void kernel_launch(void* const* d_in, const int* in_sizes, int n_in,
                              void* d_out, int out_size, void* d_ws,
                              size_t ws_size, hipStream_t stream) {
  (void)in_sizes; (void)n_in; (void)out_size; (void)ws_size;
  const int* tokens = (const int*)d_in[0];
  const float* emb = (const float*)d_in[1];
  const float* wq = (const float*)d_in[2];
  const float* wk = (const float*)d_in[3];
  const float* wv = (const float*)d_in[4];
  const float* wo = (const float*)d_in[5];
  const float* w1 = (const float*)d_in[6];
  const float* w2 = (const float*)d_in[7];
  const float* w3 = (const float*)d_in[8];
  const float* anw = (const float*)d_in[9];
  const float* fnw = (const float*)d_in[10];
  const float* finw = (const float*)d_in[11];
  float* out = (float*)d_out;

  char* p = (char*)d_ws;
  auto alloc = [&](size_t bytes) {
    char* r = p;
    p += (bytes + 255) & ~(size_t)255;
    return r;
  };
  f16* wqkv_l = (f16*)alloc((size_t)3 * DIM * DIM * 2);
  f16* wo_l = (f16*)alloc((size_t)DIM * DIM * 2);
  f16* w13_l = (f16*)alloc((size_t)2 * HIDD * DIM * 2);
  f16* w2_l = (f16*)alloc((size_t)DIM * HIDD * 2);
  float* hbuf = (float*)alloc((size_t)SEQ * DIM * 4);
  f16* x_h = (f16*)alloc((size_t)SEQ * DIM * 2);
  f16* qkv_h = (f16*)alloc((size_t)SEQ * 3 * DIM * 2);
  f16* vT_h = (f16*)alloc((size_t)DIM * SEQ * 2);
  f16* o_h = (f16*)alloc((size_t)SEQ * DIM * 2);
  f16* g13_h = (f16*)alloc((size_t)SEQ * 2 * HIDD * 2);
  f16* t_h = (f16*)alloc((size_t)SEQ * HIDD * 2);
  float* tab = (float*)alloc((size_t)SEQ * 32 * 2 * 4);
  float* hn = (float*)alloc(4096);

  embed_k<<<SEQ, 256, 0, stream>>>(tokens, emb, hbuf);
  rope_tab_k<<<(SEQ * 32 + 255) / 256, 256, 0, stream>>>(tab);

  const int CAST_BLOCKS = (4 * (DIM * DIM / 4) + 3 * (HIDD * DIM / 4)) / 256;
  for (int l = 0; l < LNUM; l++) {
    const size_t offDD = (size_t)l * DIM * DIM;
    const size_t offHD = (size_t)l * HIDD * DIM;
    cast_layer_k<<<CAST_BLOCKS, 256, 0, stream>>>(
        wq + offDD, wk + offDD, wv + offDD, wo + offDD, w1 + offHD,
        w3 + offHD, w2 + offHD, wqkv_l, wo_l, w13_l, w2_l);

    rmsnorm_k<<<SEQ, 256, 0, stream>>>(hbuf, anw + (size_t)l * DIM, x_h);
    {
      dim3 g(SEQ / 128, (3 * DIM) / 128);
      gemm_bt<0><<<g, 256, 0, stream>>>(x_h, wqkv_l, qkv_h, SEQ, 3 * DIM, DIM);
    }
    rope_k<<<(SEQ * 2 * NH * 32) / 256, 256, 0, stream>>>(qkv_h, tab);
    {
      dim3 g(SEQ / 32, DIM / 32);
      transpose_v<<<g, 256, 0, stream>>>(qkv_h, vT_h);
    }
    {
      dim3 g(SEQ / 32, NH);
      attn_k<<<g, 256, 0, stream>>>(qkv_h, vT_h, o_h);
    }
    {
      dim3 g(SEQ / 128, DIM / 128);
      gemm_bt<1><<<g, 256, 0, stream>>>(o_h, wo_l, hbuf, SEQ, DIM, DIM);
    }
    rmsnorm_k<<<SEQ, 256, 0, stream>>>(hbuf, fnw + (size_t)l * DIM, x_h);
    {
      dim3 g(SEQ / 128, (2 * HIDD) / 128);
      gemm_bt<0><<<g, 256, 0, stream>>>(x_h, w13_l, g13_h, SEQ, 2 * HIDD, DIM);
    }
    {
      dim3 g(HIDD / 256, SEQ);
      silu_k<<<g, 256, 0, stream>>>(g13_h, t_h);
    }
    {
      dim3 g(SEQ / 128, DIM / 128);
      gemm_bt<1><<<g, 256, 0, stream>>>(t_h, w2_l, hbuf, SEQ, DIM, HIDD);
    }
  }
  final_norm_k<<<1, 256, 0, stream>>>(hbuf, finw, hn);
  logits_k<<<VOCAB / 4, 256, 0, stream>>>(hn, emb, out);
}

// Round 5
// 896.098 us; speedup vs baseline: 1.4070x; 1.2757x over previous
//
#include <hip/hip_runtime.h>

#define LNUM 4
#define DIM 1024
#define NH 16
#define VOCAB 32000
#define SEQ 2048
#define HIDD 2816

typedef _Float16 f16;
typedef _Float16 h8_t __attribute__((ext_vector_type(8)));
typedef _Float16 h4_t __attribute__((ext_vector_type(4)));
typedef float f4_t __attribute__((ext_vector_type(4)));

#define MFMA(a, b, c) __builtin_amdgcn_mfma_f32_16x16x32_f16(a, b, c, 0, 0, 0)

__device__ __forceinline__ void async16(void* lds, const void* g) {
  __builtin_amdgcn_global_load_lds(
      (const __attribute__((address_space(1))) void*)g,
      (__attribute__((address_space(3))) void*)lds, 16, 0, 0);
}

// DPP row_ror butterfly primitives (16-lane rows; pure VALU, no LDS)
template <int N>
__device__ __forceinline__ float ror16(float x) {
  int r = __builtin_amdgcn_update_dpp(0, __builtin_bit_cast(int, x),
                                      0x120 | N, 0xF, 0xF, true);
  return __builtin_bit_cast(float, r);
}
__device__ __forceinline__ float rmax16(float v) {
  v = fmaxf(v, ror16<1>(v));
  v = fmaxf(v, ror16<2>(v));
  v = fmaxf(v, ror16<4>(v));
  v = fmaxf(v, ror16<8>(v));
  return v;
}
__device__ __forceinline__ float rsum16(float v) {
  v += ror16<1>(v);
  v += ror16<2>(v);
  v += ror16<4>(v);
  v += ror16<8>(v);
  return v;
}

// ---------------- fused per-layer fp32 -> fp16 weight cast ----------------
__global__ __launch_bounds__(256) void cast_layer_k(
    const float* __restrict__ wq, const float* __restrict__ wk,
    const float* __restrict__ wv, const float* __restrict__ wo,
    const float* __restrict__ w1, const float* __restrict__ w3,
    const float* __restrict__ w2, f16* __restrict__ wqkv,
    f16* __restrict__ wod, f16* __restrict__ w13, f16* __restrict__ w2d) {
  const int DD4c = DIM * DIM / 4, HD4c = HIDD * DIM / 4;
  int i = blockIdx.x * 256 + threadIdx.x;  // total 4*DD4c + 3*HD4c = 3211264
  const float* s;
  f16* d;
  int si, di;
  if (i < 3 * DD4c) {
    d = wqkv;
    di = i;
    if (i < DD4c) {
      s = wq; si = i;
    } else if (i < 2 * DD4c) {
      s = wk; si = i - DD4c;
    } else {
      s = wv; si = i - 2 * DD4c;
    }
  } else if (i < 4 * DD4c) {
    s = wo; si = i - 3 * DD4c; d = wod; di = si;
  } else if (i < 4 * DD4c + HD4c) {
    s = w1; si = i - 4 * DD4c; d = w13; di = si;
  } else if (i < 4 * DD4c + 2 * HD4c) {
    s = w3; si = i - 4 * DD4c - HD4c; d = w13; di = si + HD4c;
  } else {
    s = w2; si = i - 4 * DD4c - 2 * HD4c; d = w2d; di = si;
  }
  float4 v = ((const float4*)s)[si];
  ((h4_t*)d)[di] = (h4_t){(f16)v.x, (f16)v.y, (f16)v.z, (f16)v.w};
}

// ---------------- embedding gather ----------------
__global__ __launch_bounds__(256) void embed_k(const int* __restrict__ tok,
                                               const float* __restrict__ emb,
                                               float* __restrict__ h) {
  const int s = blockIdx.x, t = threadIdx.x;
  ((float4*)(h + (size_t)s * DIM))[t] =
      ((const float4*)(emb + (size_t)tok[s] * DIM))[t];
}

// ---------------- rope table (cos,sin per (s,f)) ----------------
__global__ void rope_tab_k(float* __restrict__ tab) {
  int i = blockIdx.x * 256 + threadIdx.x;
  if (i >= SEQ * 32) return;
  int s = i >> 5, f = i & 31;
  float inv = powf(10000.f, -(float)f * (1.f / 32.f));
  float a = (float)s * inv;
  float sn, c;
  sincosf(a, &sn, &c);
  tab[i * 2] = c;
  tab[i * 2 + 1] = sn;
}

// ---------------- rope apply in-place on q,k parts of qkv ----------------
__global__ __launch_bounds__(256) void rope_k(f16* __restrict__ qkv,
                                              const float* __restrict__ tab) {
  int i = blockIdx.x * 256 + threadIdx.x;  // SEQ*2*NH*32 = 2M
  int f = i & 31, hh = (i >> 5) & 15, part = (i >> 9) & 1, s = i >> 10;
  size_t base = (size_t)s * 3072 + part * 1024 + hh * 64 + f * 2;
  float xr = (float)qkv[base], xi = (float)qkv[base + 1];
  float c = tab[(s * 32 + f) * 2], sn = tab[(s * 32 + f) * 2 + 1];
  qkv[base] = (f16)(xr * c - xi * sn);
  qkv[base + 1] = (f16)(xr * sn + xi * c);
}

// ---------------- rmsnorm: fp32 h row -> fp16 out ----------------
__global__ __launch_bounds__(256) void rmsnorm_k(const float* __restrict__ h,
                                                 const float* __restrict__ w,
                                                 f16* __restrict__ out) {
  const int s = blockIdx.x, t = threadIdx.x;
  float4 v = ((const float4*)(h + (size_t)s * DIM))[t];
  float ss = v.x * v.x + v.y * v.y + v.z * v.z + v.w * v.w;
#pragma unroll
  for (int d = 1; d < 64; d <<= 1) ss += __shfl_xor(ss, d);
  __shared__ float red[4];
  if ((t & 63) == 0) red[t >> 6] = ss;
  __syncthreads();
  float tot = red[0] + red[1] + red[2] + red[3];
  float sc = rsqrtf(tot * (1.f / (float)DIM) + 1e-5f);
  float4 wv = ((const float4*)w)[t];
  ((h4_t*)(out + (size_t)s * DIM))[t] =
      (h4_t){(f16)(v.x * sc * wv.x), (f16)(v.y * sc * wv.y),
             (f16)(v.z * sc * wv.z), (f16)(v.w * sc * wv.w)};
}

// ---------------- final rmsnorm (row SEQ-1) -> fp32 ----------------
__global__ __launch_bounds__(256) void final_norm_k(const float* __restrict__ h,
                                                    const float* __restrict__ w,
                                                    float* __restrict__ hn) {
  const int t = threadIdx.x;
  float4 v = ((const float4*)(h + (size_t)(SEQ - 1) * DIM))[t];
  float ss = v.x * v.x + v.y * v.y + v.z * v.z + v.w * v.w;
#pragma unroll
  for (int d = 1; d < 64; d <<= 1) ss += __shfl_xor(ss, d);
  __shared__ float red[4];
  if ((t & 63) == 0) red[t >> 6] = ss;
  __syncthreads();
  float tot = red[0] + red[1] + red[2] + red[3];
  float sc = rsqrtf(tot * (1.f / (float)DIM) + 1e-5f);
  float4 wv = ((const float4*)w)[t];
  ((float4*)hn)[t] = make_float4(v.x * sc * wv.x, v.y * sc * wv.y,
                                 v.z * sc * wv.z, v.w * sc * wv.w);
}

// ---------------- logits: out[v] = hn . emb[v] (fp32) ----------------
__global__ __launch_bounds__(256) void logits_k(const float* __restrict__ hn,
                                                const float* __restrict__ emb,
                                                float* __restrict__ out) {
  const int v = blockIdx.x * 4 + (threadIdx.x >> 6);
  const int lane = threadIdx.x & 63;
  const float4* er = (const float4*)(emb + (size_t)v * DIM);
  const float4* hr = (const float4*)hn;
  float s = 0.f;
#pragma unroll
  for (int i = 0; i < 4; i++) {
    float4 a = er[lane + i * 64];
    float4 b = hr[lane + i * 64];
    s += a.x * b.x + a.y * b.y + a.z * b.z + a.w * b.w;
  }
#pragma unroll
  for (int d = 1; d < 64; d <<= 1) s += __shfl_xor(s, d);
  if (lane == 0) out[v] = s;
}

// ---------------- silu(g)*u from stacked g13 ----------------
__global__ __launch_bounds__(256) void silu_k(const f16* __restrict__ g13,
                                              f16* __restrict__ t) {
  int c = blockIdx.x * 256 + threadIdx.x;  // 0..2815
  int s = blockIdx.y;
  float g = (float)g13[(size_t)s * (2 * HIDD) + c];
  float u = (float)g13[(size_t)s * (2 * HIDD) + HIDD + c];
  float r = g / (1.f + __expf(-g)) * u;
  t[(size_t)s * HIDD + c] = (f16)r;
}

// ---------------- V transpose: vT[c][s] = qkv[s][2048+c] ----------------
__global__ __launch_bounds__(256) void transpose_v(const f16* __restrict__ qkv,
                                                   f16* __restrict__ vT) {
  __shared__ f16 tile[32][34];
  int bs = blockIdx.x * 32;
  int bc = blockIdx.y * 32;
  int tx = threadIdx.x & 31, ty = threadIdx.x >> 5;
#pragma unroll
  for (int i = ty; i < 32; i += 8)
    tile[i][tx] = qkv[(size_t)(bs + i) * 3072 + 2048 + bc + tx];
  __syncthreads();
#pragma unroll
  for (int i = ty; i < 32; i += 8)
    vT[(size_t)(bc + i) * SEQ + bs + tx] = tile[tx][i];
}

// ---------------- GEMM: C(MxN) = A(MxK) . B(NxK)^T, fp16 in, MFMA ----------
// EPI 0: write fp16 C.  EPI 1: C_f32 += acc (residual add).
template <int EPI>
__global__ __launch_bounds__(256) void gemm_bt(const f16* __restrict__ A,
                                               const f16* __restrict__ B,
                                               void* __restrict__ Cout, int M,
                                               int N, int K) {
  __shared__ __align__(16) f16 As[128 * 32];
  __shared__ __align__(16) f16 Bs[128 * 32];
  const int t = threadIdx.x;
  const int lane = t & 63;
  const int wave = t >> 6;
  const int wr = wave >> 1, wc = wave & 1;
  const int bm = blockIdx.x, bn = blockIdx.y;
  const int lr = lane & 15, lk = lane >> 4;

  const int srow = t >> 2;
  const int scol = (t & 3) * 8;
  const f16* gA = A + (size_t)(bm * 128 + srow) * K + scol;
  const f16* gB = B + (size_t)(bn * 128 + srow) * K + scol;
  f16* lA = As + t * 8;
  f16* lB = Bs + t * 8;

  f4_t acc[4][4];
#pragma unroll
  for (int m = 0; m < 4; m++)
#pragma unroll
    for (int n = 0; n < 4; n++) acc[m][n] = {0.f, 0.f, 0.f, 0.f};

  for (int k0 = 0; k0 < K; k0 += 32) {
    __syncthreads();  // previous iteration's LDS reads complete
    async16(lA, gA + k0);
    async16(lA + 64 * 32, gA + (size_t)64 * K + k0);
    async16(lB, gB + k0);
    async16(lB + 64 * 32, gB + (size_t)64 * K + k0);
    __syncthreads();  // drains vmcnt before reads
    h8_t af[4], bfr[4];
#pragma unroll
    for (int m = 0; m < 4; m++)
      af[m] = *(const h8_t*)(As + (wr * 64 + m * 16 + lr) * 32 + lk * 8);
#pragma unroll
    for (int n = 0; n < 4; n++)
      bfr[n] = *(const h8_t*)(Bs + (wc * 64 + n * 16 + lr) * 32 + lk * 8);
#pragma unroll
    for (int m = 0; m < 4; m++)
#pragma unroll
      for (int n = 0; n < 4; n++) acc[m][n] = MFMA(af[m], bfr[n], acc[m][n]);
  }

  const int orow = bm * 128 + wr * 64 + lk * 4;
  const int ocol = bn * 128 + wc * 64 + lr;
#pragma unroll
  for (int m = 0; m < 4; m++)
#pragma unroll
    for (int n = 0; n < 4; n++)
#pragma unroll
      for (int j = 0; j < 4; j++) {
        int r = orow + m * 16 + j;
        int c = ocol + n * 16;
        if (EPI == 0) {
          ((f16*)Cout)[(size_t)r * N + c] = (f16)acc[m][n][j];
        } else {
          float* pC = (float*)Cout + (size_t)r * N + c;
          *pC += acc[m][n][j];
        }
      }
}

// ------- split-K GEMM: partial C slice (fp32) per blockIdx.z -------
// C_part[z](MxN) = A(:, z*Ks..)(M x Ks) . B(:, z*Ks..)^T ; ld = full K stride.
__global__ __launch_bounds__(256) void gemm_skp(const f16* __restrict__ A,
                                                const f16* __restrict__ B,
                                                float* __restrict__ Cp, int N,
                                                int ld, int Ks) {
  __shared__ __align__(16) f16 As[128 * 32];
  __shared__ __align__(16) f16 Bs[128 * 32];
  const int t = threadIdx.x;
  const int lane = t & 63;
  const int wave = t >> 6;
  const int wr = wave >> 1, wc = wave & 1;
  const int bm = blockIdx.x, bn = blockIdx.y, bk = blockIdx.z;
  const int lr = lane & 15, lk = lane >> 4;

  const f16* Ao = A + (size_t)bk * Ks;
  const f16* Bo = B + (size_t)bk * Ks;
  float* Cout = Cp + (size_t)bk * gridDim.x * 128 * N;

  const int srow = t >> 2;
  const int scol = (t & 3) * 8;
  const f16* gA = Ao + (size_t)(bm * 128 + srow) * ld + scol;
  const f16* gB = Bo + (size_t)(bn * 128 + srow) * ld + scol;
  f16* lA = As + t * 8;
  f16* lB = Bs + t * 8;

  f4_t acc[4][4];
#pragma unroll
  for (int m = 0; m < 4; m++)
#pragma unroll
    for (int n = 0; n < 4; n++) acc[m][n] = {0.f, 0.f, 0.f, 0.f};

  for (int k0 = 0; k0 < Ks; k0 += 32) {
    __syncthreads();
    async16(lA, gA + k0);
    async16(lA + 64 * 32, gA + (size_t)64 * ld + k0);
    async16(lB, gB + k0);
    async16(lB + 64 * 32, gB + (size_t)64 * ld + k0);
    __syncthreads();
    h8_t af[4], bfr[4];
#pragma unroll
    for (int m = 0; m < 4; m++)
      af[m] = *(const h8_t*)(As + (wr * 64 + m * 16 + lr) * 32 + lk * 8);
#pragma unroll
    for (int n = 0; n < 4; n++)
      bfr[n] = *(const h8_t*)(Bs + (wc * 64 + n * 16 + lr) * 32 + lk * 8);
#pragma unroll
    for (int m = 0; m < 4; m++)
#pragma unroll
      for (int n = 0; n < 4; n++) acc[m][n] = MFMA(af[m], bfr[n], acc[m][n]);
  }

  const int orow = bm * 128 + wr * 64 + lk * 4;
  const int ocol = bn * 128 + wc * 64 + lr;
#pragma unroll
  for (int m = 0; m < 4; m++)
#pragma unroll
    for (int n = 0; n < 4; n++)
#pragma unroll
      for (int j = 0; j < 4; j++)
        Cout[(size_t)(orow + m * 16 + j) * N + ocol + n * 16] = acc[m][n][j];
}

// h[i] += p0[i] + p1[i]  (fp32, float4)
__global__ __launch_bounds__(256) void sk_reduce_k(const float* __restrict__ p,
                                                   float* __restrict__ h,
                                                   int n4) {
  int i = blockIdx.x * 256 + threadIdx.x;
  if (i >= n4) return;
  float4 a = ((const float4*)p)[i];
  float4 b = ((const float4*)p)[i + n4];
  float4 c = ((float4*)h)[i];
  c.x += a.x + b.x;
  c.y += a.y + b.y;
  c.z += a.z + b.z;
  c.w += a.w + b.w;
  ((float4*)h)[i] = c;
}

// ---------------- flash attention, KV-split across 4 waves ------------
// Grid (NH, SEQ/32): head = blockIdx.x so linear id % 8 == head % 8 ->
// each XCD serves 2 heads; K/V stays L2-resident (1 MB/XCD).
__global__ __launch_bounds__(256) void attn_k(const f16* __restrict__ qkv,
                                              const f16* __restrict__ vT,
                                              f16* __restrict__ o) {
  const int hh = blockIdx.x;
  const int qb = blockIdx.y;
  const int tid = threadIdx.x;
  const int wave = tid >> 6;
  const int lane = tid & 63;
  const int lr = lane & 15, lk = lane >> 4;
  const int q0 = qb * 32;
  __shared__ __align__(16) char P[4][4096];  // per-wave P, XOR-swizzled
  __shared__ float MB[3][64][48];            // waves 1..3 partials

  h8_t qf[2][2];
#pragma unroll
  for (int m = 0; m < 2; m++)
#pragma unroll
    for (int ks = 0; ks < 2; ks++)
      qf[m][ks] = *(const h8_t*)(qkv + (size_t)(q0 + m * 16 + lr) * 3072 +
                                 hh * 64 + ks * 32 + lk * 8);

  float mrow[2][4], lsum[2][4];
  f4_t oacc[2][4];
#pragma unroll
  for (int m = 0; m < 2; m++)
#pragma unroll
    for (int j = 0; j < 4; j++) {
      mrow[m][j] = -1e30f;
      lsum[m][j] = 0.f;
    }
#pragma unroll
  for (int m = 0; m < 2; m++)
#pragma unroll
    for (int n = 0; n < 4; n++) oacc[m][n] = {0.f, 0.f, 0.f, 0.f};

  const int ntiles = (qb >> 1) + 1;
  char* Pw = P[wave];
  for (int kt = wave; kt < ntiles; kt += 4) {
    f4_t sacc[2][4];
#pragma unroll
    for (int m = 0; m < 2; m++)
#pragma unroll
      for (int n = 0; n < 4; n++) sacc[m][n] = {0.f, 0.f, 0.f, 0.f};
#pragma unroll
    for (int ks = 0; ks < 2; ks++) {
      h8_t kf[4];
#pragma unroll
      for (int n = 0; n < 4; n++)
        kf[n] = *(const h8_t*)(qkv + (size_t)(kt * 64 + n * 16 + lr) * 3072 +
                               1024 + hh * 64 + ks * 32 + lk * 8);
#pragma unroll
      for (int m = 0; m < 2; m++)
#pragma unroll
        for (int n = 0; n < 4; n++)
          sacc[m][n] = MFMA(qf[m][ks], kf[n], sacc[m][n]);
    }
    const bool lastt = (kt == ntiles - 1);
    float pv[2][4][4];
#pragma unroll
    for (int m = 0; m < 2; m++)
#pragma unroll
      for (int n = 0; n < 4; n++)
#pragma unroll
        for (int j = 0; j < 4; j++) {
          float sv = sacc[m][n][j] * 0.125f;
          if (lastt && (kt * 64 + n * 16 + lr) > (q0 + m * 16 + lk * 4 + j))
            sv = -1e30f;
          pv[m][n][j] = sv;
        }
    // online softmax (rows live on 16 lanes sharing lk) — DPP reductions
#pragma unroll
    for (int m = 0; m < 2; m++)
#pragma unroll
      for (int j = 0; j < 4; j++) {
        float mx = fmaxf(fmaxf(pv[m][0][j], pv[m][1][j]),
                         fmaxf(pv[m][2][j], pv[m][3][j]));
        mx = rmax16(mx);
        float mnew = fmaxf(mrow[m][j], mx);
        float corr = __expf(mrow[m][j] - mnew);
        mrow[m][j] = mnew;
        float rs = 0.f;
#pragma unroll
        for (int n = 0; n < 4; n++) {
          float pe = __expf(pv[m][n][j] - mnew);
          pv[m][n][j] = pe;
          rs += pe;
        }
        rs = rsum16(rs);
        lsum[m][j] = lsum[m][j] * corr + rs;
#pragma unroll
        for (int n = 0; n < 4; n++) oacc[m][n][j] *= corr;
      }
    // P round-trip: per-wave private LDS, same-wave DS ops are ordered.
#pragma unroll
    for (int m = 0; m < 2; m++)
#pragma unroll
      for (int n = 0; n < 4; n++)
#pragma unroll
        for (int j = 0; j < 4; j++) {
          int r = m * 16 + lk * 4 + j, c = n * 16 + lr;
          int off = (r * 128 + c * 2) ^ ((r & 7) << 4);
          *(f16*)(Pw + off) = (f16)pv[m][n][j];
        }
#pragma unroll
    for (int ks = 0; ks < 2; ks++) {
      h8_t pf[2], vf[4];
#pragma unroll
      for (int m = 0; m < 2; m++) {
        int r = m * 16 + lr;
        int off = (r * 128 + ks * 64 + lk * 16) ^ ((r & 7) << 4);
        pf[m] = *(const h8_t*)(Pw + off);
      }
#pragma unroll
      for (int n = 0; n < 4; n++)
        vf[n] = *(const h8_t*)(vT + (size_t)(hh * 64 + n * 16 + lr) * SEQ +
                               kt * 64 + ks * 32 + lk * 8);
#pragma unroll
      for (int m = 0; m < 2; m++)
#pragma unroll
        for (int n = 0; n < 4; n++)
          oacc[m][n] = MFMA(pf[m], vf[n], oacc[m][n]);
    }
  }

  // ---- cross-wave LSE merge ----
  if (wave > 0) {
    float* d = &MB[wave - 1][lane][0];
#pragma unroll
    for (int m = 0; m < 2; m++)
#pragma unroll
      for (int j = 0; j < 4; j++) {
        d[m * 4 + j] = mrow[m][j];
        d[8 + m * 4 + j] = lsum[m][j];
      }
#pragma unroll
    for (int m = 0; m < 2; m++)
#pragma unroll
      for (int n = 0; n < 4; n++)
#pragma unroll
        for (int j = 0; j < 4; j++)
          d[16 + m * 16 + n * 4 + j] = oacc[m][n][j];
  }
  __syncthreads();
  if (wave == 0) {
#pragma unroll
    for (int m = 0; m < 2; m++)
#pragma unroll
      for (int j = 0; j < 4; j++) {
        float M = mrow[m][j];
#pragma unroll
        for (int w = 0; w < 3; w++) M = fmaxf(M, MB[w][lane][m * 4 + j]);
        float sc0 = __expf(mrow[m][j] - M);
        float L = lsum[m][j] * sc0;
        float scw[3];
#pragma unroll
        for (int w = 0; w < 3; w++) {
          scw[w] = __expf(MB[w][lane][m * 4 + j] - M);
          L += MB[w][lane][8 + m * 4 + j] * scw[w];
        }
        float invL = 1.f / L;
#pragma unroll
        for (int n = 0; n < 4; n++) {
          float val = oacc[m][n][j] * sc0;
#pragma unroll
          for (int w = 0; w < 3; w++)
            val += MB[w][lane][16 + m * 16 + n * 4 + j] * scw[w];
          o[(size_t)(q0 + m * 16 + lk * 4 + j) * DIM + hh * 64 + n * 16 + lr] =
              (f16)(val * invL);
        }
      }
  }
}

extern "C" void kernel_launch(void* const* d_in, const int* in_sizes, int n_in,
                              void* d_out, int out_size, void* d_ws,
                              size_t ws_size, hipStream_t stream) {
  (void)in_sizes; (void)n_in; (void)out_size; (void)ws_size;
  const int* tokens = (const int*)d_in[0];
  const float* emb = (const float*)d_in[1];
  const float* wq = (const float*)d_in[2];
  const float* wk = (const float*)d_in[3];
  const float* wv = (const float*)d_in[4];
  const float* wo = (const float*)d_in[5];
  const float* w1 = (const float*)d_in[6];
  const float* w2 = (const float*)d_in[7];
  const float* w3 = (const float*)d_in[8];
  const float* anw = (const float*)d_in[9];
  const float* fnw = (const float*)d_in[10];
  const float* finw = (const float*)d_in[11];
  float* out = (float*)d_out;

  char* p = (char*)d_ws;
  auto alloc = [&](size_t bytes) {
    char* r = p;
    p += (bytes + 255) & ~(size_t)255;
    return r;
  };
  f16* wqkv_l = (f16*)alloc((size_t)3 * DIM * DIM * 2);
  f16* wo_l = (f16*)alloc((size_t)DIM * DIM * 2);
  f16* w13_l = (f16*)alloc((size_t)2 * HIDD * DIM * 2);
  f16* w2_l = (f16*)alloc((size_t)DIM * HIDD * 2);
  float* hbuf = (float*)alloc((size_t)SEQ * DIM * 4);
  f16* x_h = (f16*)alloc((size_t)SEQ * DIM * 2);
  f16* qkv_h = (f16*)alloc((size_t)SEQ * 3 * DIM * 2);
  f16* vT_h = (f16*)alloc((size_t)DIM * SEQ * 2);
  f16* o_h = (f16*)alloc((size_t)SEQ * DIM * 2);
  f16* g13_h = (f16*)alloc((size_t)SEQ * 2 * HIDD * 2);
  f16* t_h = (f16*)alloc((size_t)SEQ * HIDD * 2);
  float* skbuf = (float*)alloc((size_t)2 * SEQ * DIM * 4);
  float* tab = (float*)alloc((size_t)SEQ * 32 * 2 * 4);
  float* hn = (float*)alloc(4096);

  embed_k<<<SEQ, 256, 0, stream>>>(tokens, emb, hbuf);
  rope_tab_k<<<(SEQ * 32 + 255) / 256, 256, 0, stream>>>(tab);

  const int CAST_BLOCKS = (4 * (DIM * DIM / 4) + 3 * (HIDD * DIM / 4)) / 256;
  const int N4 = SEQ * DIM / 4;
  for (int l = 0; l < LNUM; l++) {
    const size_t offDD = (size_t)l * DIM * DIM;
    const size_t offHD = (size_t)l * HIDD * DIM;
    cast_layer_k<<<CAST_BLOCKS, 256, 0, stream>>>(
        wq + offDD, wk + offDD, wv + offDD, wo + offDD, w1 + offHD,
        w3 + offHD, w2 + offHD, wqkv_l, wo_l, w13_l, w2_l);

    rmsnorm_k<<<SEQ, 256, 0, stream>>>(hbuf, anw + (size_t)l * DIM, x_h);
    {
      dim3 g(SEQ / 128, (3 * DIM) / 128);
      gemm_bt<0><<<g, 256, 0, stream>>>(x_h, wqkv_l, qkv_h, SEQ, 3 * DIM, DIM);
    }
    rope_k<<<(SEQ * 2 * NH * 32) / 256, 256, 0, stream>>>(qkv_h, tab);
    {
      dim3 g(SEQ / 32, DIM / 32);
      transpose_v<<<g, 256, 0, stream>>>(qkv_h, vT_h);
    }
    {
      dim3 g(NH, SEQ / 32);  // head-major -> head%8 == XCD affinity
      attn_k<<<g, 256, 0, stream>>>(qkv_h, vT_h, o_h);
    }
    {
      // O-proj split-K: K=1024 -> 2x512
      dim3 g(SEQ / 128, DIM / 128, 2);
      gemm_skp<<<g, 256, 0, stream>>>(o_h, wo_l, skbuf, DIM, DIM, DIM / 2);
      sk_reduce_k<<<(N4 + 255) / 256, 256, 0, stream>>>(skbuf, hbuf, N4);
    }
    rmsnorm_k<<<SEQ, 256, 0, stream>>>(hbuf, fnw + (size_t)l * DIM, x_h);
    {
      dim3 g(SEQ / 128, (2 * HIDD) / 128);
      gemm_bt<0><<<g, 256, 0, stream>>>(x_h, w13_l, g13_h, SEQ, 2 * HIDD, DIM);
    }
    {
      dim3 g(HIDD / 256, SEQ);
      silu_k<<<g, 256, 0, stream>>>(g13_h, t_h);
    }
    {
      // W2 split-K: K=2816 -> 2x1408
      dim3 g(SEQ / 128, DIM / 128, 2);
      gemm_skp<<<g, 256, 0, stream>>>(t_h, w2_l, skbuf, DIM, HIDD, HIDD / 2);
      sk_reduce_k<<<(N4 + 255) / 256, 256, 0, stream>>>(skbuf, hbuf, N4);
    }
  }
  final_norm_k<<<1, 256, 0, stream>>>(hbuf, finw, hn);
  logits_k<<<VOCAB / 4, 256, 0, stream>>>(hn, emb, out);
}